// Round 1
// baseline (206.065 us; speedup 1.0000x reference)
//
#include <hip/hip_runtime.h>
#include <math.h>

// Problem constants (B=8, T=1024, H=640, N_PHONE=230, N_PHONEME=96)
#define NB 8
#define NT 1024
#define NH 640
#define NP 230
#define NM 96
#define NROWS (NB * NT)   // 8192
#define RT 32             // rows per block
#define KT 32             // K chunk
#define NPAD 256          // padded phone columns in LDS
#define MAXL 64           // max phones per phoneme in CSR

// Kernel 0: build CSR (phoneme -> list of phones with mapping>0) into ws.
// Must run every call: ws is re-poisoned before every timed launch.
__global__ void build_csr_kernel(const float* __restrict__ mapping,
                                 int* __restrict__ cnt, int* __restrict__ csr) {
    int m = threadIdx.x;
    if (m >= NM) return;
    int c = 0;
    for (int p = 0; p < NP; ++p) {
        if (mapping[m * NP + p] > 0.0f) {
            if (c < MAXL) csr[m * MAXL + c] = p;
            ++c;
        }
    }
    cnt[m] = (c < MAXL) ? c : MAXL;
}

// Fused: GEMM (32 rows x 230 phones, K=640) -> masked segment max -> log_softmax
__global__ __launch_bounds__(256)
void fused_phonetics_kernel(const float* __restrict__ enc,
                            const float* __restrict__ f2p,
                            const int* __restrict__ cnt,
                            const int* __restrict__ csr,
                            float* __restrict__ out) {
    __shared__ float sA[KT][RT + 2];      // [k][row], stride 34 (even, conflict-free)
    __shared__ float sB[KT * NPAD];       // [k][p]; reused as phone[RT][NPAD] in epilogue
    __shared__ float pm[RT][NM + 1];      // phoneme maxes, +1 pad breaks 32-bank stride
    __shared__ float rstat[RT][2];        // per-row {max, logsumexp}

    const int tid = threadIdx.x;
    const int tc  = tid & 15;             // col group 0..15
    const int tr  = tid >> 4;             // row group 0..15 -> rows tr*2, tr*2+1
    const int tr2 = tr * 2;
    const int tc4 = tc * 4;
    const int row0 = blockIdx.x * RT;

    float acc0[16], acc1[16];
    #pragma unroll
    for (int i = 0; i < 16; ++i) { acc0[i] = 0.f; acc1[i] = 0.f; }

    // staging thread mappings
    const int sr  = tid >> 3;   // A: row 0..31
    const int skq = tid & 7;    // A: float4 index along k
    const int bkk = tid >> 3;   // B: k row 0..31
    const int bp0 = tid & 7;    // B: phone start

    for (int k0 = 0; k0 < NH; k0 += KT) {
        // --- stage A tile, transposed to [k][row]; coalesced float4 global loads
        float4 av = *(const float4*)(enc + (size_t)(row0 + sr) * NH + k0 + skq * 4);
        sA[skq * 4 + 0][sr] = av.x;
        sA[skq * 4 + 1][sr] = av.y;
        sA[skq * 4 + 2][sr] = av.z;
        sA[skq * 4 + 3][sr] = av.w;
        // --- stage B tile [k][p], zero-fill pad cols 230..255
        {
            const float* src = f2p + (size_t)(k0 + bkk) * NP;
            float* dst = sB + bkk * NPAD;
            #pragma unroll
            for (int j = 0; j < 32; ++j) {
                int p = bp0 + j * 8;
                dst[p] = (p < NP) ? src[p] : 0.0f;
            }
        }
        __syncthreads();
        // --- compute: per k, 1 b64 (A) + 4 b128 (B) LDS reads, 32 FMAs
        #pragma unroll
        for (int k = 0; k < KT; ++k) {
            float2 a = *(const float2*)&sA[k][tr2];
            const float* brow = sB + k * NPAD + tc4;
            float4 b0 = *(const float4*)(brow);
            float4 b1 = *(const float4*)(brow + 64);
            float4 b2 = *(const float4*)(brow + 128);
            float4 b3 = *(const float4*)(brow + 192);
            float bv[16] = { b0.x, b0.y, b0.z, b0.w,
                             b1.x, b1.y, b1.z, b1.w,
                             b2.x, b2.y, b2.z, b2.w,
                             b3.x, b3.y, b3.z, b3.w };
            #pragma unroll
            for (int i = 0; i < 16; ++i) {
                acc0[i] = fmaf(a.x, bv[i], acc0[i]);
                acc1[i] = fmaf(a.y, bv[i], acc1[i]);
            }
        }
        __syncthreads();
    }

    // --- epilogue: phone logits (scaled) into sB as phone[RT][NPAD]
    const float scale = 0.03952847075210474f;  // 1/sqrt(640)
    #pragma unroll
    for (int g = 0; g < 4; ++g) {
        float4 v0 = make_float4(acc0[g*4+0] * scale, acc0[g*4+1] * scale,
                                acc0[g*4+2] * scale, acc0[g*4+3] * scale);
        float4 v1 = make_float4(acc1[g*4+0] * scale, acc1[g*4+1] * scale,
                                acc1[g*4+2] * scale, acc1[g*4+3] * scale);
        *(float4*)&sB[(size_t)tr2       * NPAD + g * 64 + tc4] = v0;
        *(float4*)&sB[(size_t)(tr2 + 1) * NPAD + g * 64 + tc4] = v1;
    }
    __syncthreads();

    // --- masked segment max via CSR: (row, phoneme) pairs
    for (int q = tid; q < RT * NM; q += 256) {
        int r = q / NM;
        int m = q - r * NM;
        int c = cnt[m];
        float best = -INFINITY;
        for (int j = 0; j < c; ++j) {
            int p = csr[m * MAXL + j];
            best = fmaxf(best, sB[r * NPAD + p]);
        }
        pm[r][m] = best;
    }
    __syncthreads();

    // --- per-row max + logsumexp (one thread per row)
    if (tid < RT) {
        float mx = -INFINITY;
        #pragma unroll 8
        for (int m = 0; m < NM; ++m) mx = fmaxf(mx, pm[tid][m]);
        float s = 0.f;
        #pragma unroll 8
        for (int m = 0; m < NM; ++m) s += __expf(pm[tid][m] - mx);
        rstat[tid][0] = mx;
        rstat[tid][1] = mx + __logf(s);
    }
    __syncthreads();

    // --- write log_softmax, coalesced
    for (int q = tid; q < RT * NM; q += 256) {
        int r = q / NM;
        int m = q - r * NM;
        out[(size_t)row0 * NM + q] = pm[r][m] - rstat[r][1];
    }
}

extern "C" void kernel_launch(void* const* d_in, const int* in_sizes, int n_in,
                              void* d_out, int out_size, void* d_ws, size_t ws_size,
                              hipStream_t stream) {
    const float* enc     = (const float*)d_in[0];   // (8,1024,640) f32
    const float* f2p     = (const float*)d_in[1];   // (640,230) f32
    const float* mapping = (const float*)d_in[2];   // (96,230) f32
    float* out = (float*)d_out;                     // (8,1024,96) f32

    int* cnt = (int*)d_ws;        // 96 ints
    int* csr = cnt + NM;          // 96*64 ints

    build_csr_kernel<<<1, 128, 0, stream>>>(mapping, cnt, csr);
    fused_phonetics_kernel<<<NROWS / RT, 256, 0, stream>>>(enc, f2p, cnt, csr, out);
}

// Round 2
// 103.837 us; speedup vs baseline: 1.9845x; 1.9845x over previous
//
#include <hip/hip_runtime.h>
#include <math.h>

// Problem constants (B=8, T=1024, H=640, N_PHONE=230, N_PHONEME=96)
#define NH 640
#define NP 230
#define NM 96
#define NROWS 8192
#define MAXL 32          // max phones per phoneme (actual nnz/phoneme ~5, tail ~10)
#define MBLK 16          // rows per block -> grid 512, 2 blocks/CU

typedef __bf16 bf16_t;
typedef bf16_t bf16x8 __attribute__((ext_vector_type(8)));
typedef float floatx4 __attribute__((ext_vector_type(4)));

// fp32 -> bf16 round-to-nearest-even (bit-exact, no __bf16 arithmetic needed)
static __device__ __forceinline__ unsigned short f2b(float f) {
    unsigned u = __float_as_uint(f);
    u += 0x7fffu + ((u >> 16) & 1u);
    return (unsigned short)(u >> 16);
}

// ---------------- Prep 1: CSR build, one WAVE per phoneme (ballot compaction)
__global__ void build_csr_kernel(const float* __restrict__ mapping,
                                 int* __restrict__ cnt, int* __restrict__ csr) {
    int wave = (int)((blockIdx.x * blockDim.x + threadIdx.x) >> 6);
    int lane = threadIdx.x & 63;
    if (wave >= NM) return;
    int base = 0;
    #pragma unroll
    for (int c = 0; c < 4; ++c) {
        int p = c * 64 + lane;
        float v = (p < NP) ? mapping[wave * NP + p] : 0.0f;
        unsigned long long mask = __ballot(v > 0.0f);
        if (v > 0.0f) {
            int idx = base + __popcll(mask & ((1ull << lane) - 1ull));
            if (idx < MAXL) csr[wave * MAXL + idx] = p;
        }
        base += __popcll(mask);
    }
    if (lane == 0) cnt[wave] = base < MAXL ? base : MAXL;
}

// ---------------- Prep 2: B^T bf16 into ws: wsB[n][k], n padded 230->256 (zeros)
__global__ void transpose_b_kernel(const float* __restrict__ f2p,
                                   unsigned short* __restrict__ wsB) {
    __shared__ float tile[32][33];
    int kt = blockIdx.x % 20;           // 640/32 k-tiles
    int nt = blockIdx.x / 20;           // 256/32 n-tiles
    int k0 = kt * 32, n0 = nt * 32;
    int tx = threadIdx.x & 31, ty = threadIdx.x >> 5;   // ty 0..7
    #pragma unroll
    for (int it = 0; it < 4; ++it) {
        int k = k0 + ty + it * 8;
        int n = n0 + tx;
        tile[ty + it * 8][tx] = (n < NP) ? f2p[k * NP + n] : 0.0f;
    }
    __syncthreads();
    #pragma unroll
    for (int it = 0; it < 4; ++it) {
        int n = ty + it * 8;
        wsB[(size_t)(n0 + n) * NH + k0 + tx] = f2b(tile[tx][n]);
    }
}

// ---------------- Main: barrier-free MFMA K-loop + fused segmax/log_softmax
// Block: 256 thr (4 waves). Wave w computes rows [row0,row0+16) x cols [w*64,(w+1)*64)
// via 4x mfma_f32_16x16x32_bf16. A from global fp32 (inline cvt), B^T from ws (L2).
__global__ __launch_bounds__(256, 2)
void fused_phonetics_kernel(const float* __restrict__ enc,
                            const unsigned short* __restrict__ wsB,
                            const int* __restrict__ cnt,
                            const int* __restrict__ csr,
                            float* __restrict__ out) {
    __shared__ float phone[MBLK][257];   // [row][phone], odd stride: ~conflict-free

    const int tid  = threadIdx.x;
    const int lane = tid & 63;
    const int wv   = tid >> 6;          // wave 0..3
    const int m16  = lane & 15;
    const int quad = lane >> 4;         // 0..3
    const int row0 = blockIdx.x * MBLK;

    floatx4 acc0 = {0.f,0.f,0.f,0.f}, acc1 = acc0, acc2 = acc0, acc3 = acc0;

    // A: lane holds A[m=lane&15][k = k0 + quad*8 + 0..7]
    const float* arow = enc + (size_t)(row0 + m16) * NH + quad * 8;
    // B: lane holds B^T[n][k], n = n0 + lane&15, same k slice
    const unsigned short* brow = wsB + (size_t)(wv * 64 + m16) * NH + quad * 8;

    #pragma unroll
    for (int k0 = 0; k0 < NH; k0 += 32) {
        float4 a0 = *(const float4*)(arow + k0);
        float4 a1 = *(const float4*)(arow + k0 + 4);
        union { unsigned short s[8]; bf16x8 v; } au;
        au.s[0] = f2b(a0.x); au.s[1] = f2b(a0.y);
        au.s[2] = f2b(a0.z); au.s[3] = f2b(a0.w);
        au.s[4] = f2b(a1.x); au.s[5] = f2b(a1.y);
        au.s[6] = f2b(a1.z); au.s[7] = f2b(a1.w);
        bf16x8 af = au.v;

        uint4 b0 = *(const uint4*)(brow + k0);
        uint4 b1 = *(const uint4*)(brow + 16 * NH + k0);
        uint4 b2 = *(const uint4*)(brow + 32 * NH + k0);
        uint4 b3 = *(const uint4*)(brow + 48 * NH + k0);

        acc0 = __builtin_amdgcn_mfma_f32_16x16x32_bf16(af, __builtin_bit_cast(bf16x8, b0), acc0, 0, 0, 0);
        acc1 = __builtin_amdgcn_mfma_f32_16x16x32_bf16(af, __builtin_bit_cast(bf16x8, b1), acc1, 0, 0, 0);
        acc2 = __builtin_amdgcn_mfma_f32_16x16x32_bf16(af, __builtin_bit_cast(bf16x8, b2), acc2, 0, 0, 0);
        acc3 = __builtin_amdgcn_mfma_f32_16x16x32_bf16(af, __builtin_bit_cast(bf16x8, b3), acc3, 0, 0, 0);
    }

    // C/D layout: col = lane&15, row = quad*4 + reg  (verified m89/m91)
    const float scale = 0.03952847075210474f;  // 1/sqrt(640)
    #pragma unroll
    for (int i = 0; i < 4; ++i) {
        int r = quad * 4 + i;
        phone[r][wv * 64 +  0 + m16] = acc0[i] * scale;
        phone[r][wv * 64 + 16 + m16] = acc1[i] * scale;
        phone[r][wv * 64 + 32 + m16] = acc2[i] * scale;
        phone[r][wv * 64 + 48 + m16] = acc3[i] * scale;
    }
    __syncthreads();

    // seg-max + log_softmax: 16 threads per row; thread handles m = l16 + 16j (j<6)
    const int r   = tid >> 4;
    const int l16 = tid & 15;
    float pmv[6];
    float mx = -INFINITY;
    #pragma unroll
    for (int j = 0; j < 6; ++j) {
        int m = l16 + j * 16;
        int c = cnt[m];
        const int* lst = csr + m * MAXL;
        float best = -INFINITY;
        for (int jj = 0; jj < c; ++jj) best = fmaxf(best, phone[r][lst[jj]]);
        pmv[j] = best;
        mx = fmaxf(mx, best);
    }
    #pragma unroll
    for (int d = 1; d < 16; d <<= 1) mx = fmaxf(mx, __shfl_xor(mx, d));
    float s = 0.f;
    #pragma unroll
    for (int j = 0; j < 6; ++j) s += __expf(pmv[j] - mx);
    #pragma unroll
    for (int d = 1; d < 16; d <<= 1) s += __shfl_xor(s, d);
    const float lse = mx + __logf(s);
    #pragma unroll
    for (int j = 0; j < 6; ++j)
        out[(size_t)(row0 + r) * NM + l16 + j * 16] = pmv[j] - lse;
}

extern "C" void kernel_launch(void* const* d_in, const int* in_sizes, int n_in,
                              void* d_out, int out_size, void* d_ws, size_t ws_size,
                              hipStream_t stream) {
    const float* enc     = (const float*)d_in[0];   // (8,1024,640) f32
    const float* f2p     = (const float*)d_in[1];   // (640,230) f32
    const float* mapping = (const float*)d_in[2];   // (96,230) f32
    float* out = (float*)d_out;                     // (8,1024,96) f32

    // ws layout: cnt[96] | csr[96*32] | (align 16K) wsB[256*640] bf16  (~336 KB)
    int* cnt = (int*)d_ws;
    int* csr = cnt + NM;
    unsigned short* wsB = (unsigned short*)((char*)d_ws + 16384);

    build_csr_kernel<<<24, 256, 0, stream>>>(mapping, cnt, csr);
    transpose_b_kernel<<<160, 256, 0, stream>>>(f2p, wsB);
    fused_phonetics_kernel<<<NROWS / MBLK, 256, 0, stream>>>(enc, wsB, cnt, csr, out);
}

// Round 3
// 88.347 us; speedup vs baseline: 2.3325x; 1.1753x over previous
//
#include <hip/hip_runtime.h>
#include <math.h>

// Problem constants (B=8, T=1024, H=640, N_PHONE=230, N_PHONEME=96)
#define NH 640
#define NP 230
#define NM 96
#define NROWS 8192
#define MAXL 32
#define NSTEP 20            // K-steps of 32
#define NCT 16              // 16 col-tiles of 16 (256 padded phones)
#define NRT 512             // row-tiles of 16

// ws layout (byte offsets)
#define OFF_CNT  0
#define OFF_CSR  4096
#define OFF_B    65536      // wsB2: 20*16*64*8 bf16 = 1.25 MB? no: 20480*16B = 327,680 B
#define OFF_A    1048576    // wsA: 655360*16B = 10.5 MB

typedef __bf16 bf16_t;
typedef bf16_t bf16x8 __attribute__((ext_vector_type(8)));
typedef float floatx4 __attribute__((ext_vector_type(4)));

// fp32 -> bf16 round-to-nearest-even
static __device__ __forceinline__ unsigned short f2b(float f) {
    unsigned u = __float_as_uint(f);
    u += 0x7fffu + ((u >> 16) & 1u);
    return (unsigned short)(u >> 16);
}

// ---------------- Combined prep: CSR build + B retile + A retile (one launch)
// blocks 0..23    : CSR (one wave per phoneme)
// blocks 24..103  : B retile  -> wsB2[g]*8 bf16, g=((s*16+ct)*64+lane), elem (n,k)
// blocks 104..2663: A retile  -> wsA[h]*8 bf16,  h=((rt*20+s)*4+quad)*16+m16
__global__ __launch_bounds__(256)
void prep_kernel(const float* __restrict__ enc,
                 const float* __restrict__ f2p,
                 const float* __restrict__ mapping,
                 int* __restrict__ cnt, int* __restrict__ csr,
                 unsigned short* __restrict__ wsB2,
                 unsigned short* __restrict__ wsA) {
    const int b = blockIdx.x;
    const int tid = threadIdx.x;
    if (b < 24) {
        int wave = b * 4 + (tid >> 6);
        int lane = tid & 63;
        if (wave >= NM) return;
        int base = 0;
        #pragma unroll
        for (int c = 0; c < 4; ++c) {
            int p = c * 64 + lane;
            float v = (p < NP) ? mapping[wave * NP + p] : 0.0f;
            unsigned long long mask = __ballot(v > 0.0f);
            if (v > 0.0f) {
                int idx = base + __popcll(mask & ((1ull << lane) - 1ull));
                if (idx < MAXL) csr[wave * MAXL + idx] = p;
            }
            base += __popcll(mask);
        }
        if (lane == 0) cnt[wave] = base < MAXL ? base : MAXL;
    } else if (b < 104) {
        int g = (b - 24) * 256 + tid;          // < 20480
        int m16  = g & 15;
        int quad = (g >> 4) & 3;
        int ct   = (g >> 6) & 15;
        int s    = g >> 10;
        int n = ct * 16 + m16;
        int k0 = s * 32 + quad * 8;
        unsigned short v[8];
        #pragma unroll
        for (int j = 0; j < 8; ++j)
            v[j] = (n < NP) ? f2b(f2p[(size_t)(k0 + j) * NP + n]) : (unsigned short)0;
        *(uint4*)(wsB2 + (size_t)g * 8) = *(const uint4*)v;
    } else {
        int h = (b - 104) * 256 + tid;         // < 655360
        int m16  = h & 15;
        int quad = (h >> 4) & 3;
        int rs   = h >> 6;                     // rt*20 + s
        int s    = rs % 20;
        int rt   = rs / 20;
        const float* src = enc + (size_t)(rt * 16 + m16) * NH + s * 32 + quad * 8;
        float4 a0 = *(const float4*)(src);
        float4 a1 = *(const float4*)(src + 4);
        unsigned short v[8];
        v[0] = f2b(a0.x); v[1] = f2b(a0.y); v[2] = f2b(a0.z); v[3] = f2b(a0.w);
        v[4] = f2b(a1.x); v[5] = f2b(a1.y); v[6] = f2b(a1.z); v[7] = f2b(a1.w);
        *(uint4*)(wsA + (size_t)h * 8) = *(const uint4*)v;
    }
}

// ---------------- Main: barrier-free MFMA K-loop, all loads lane-linear (1 txn/instr)
__global__ __launch_bounds__(256, 2)
void fused_phonetics_kernel(const unsigned short* __restrict__ wsA,
                            const unsigned short* __restrict__ wsB2,
                            const int* __restrict__ cnt,
                            const int* __restrict__ csr,
                            float* __restrict__ out) {
    __shared__ float phone[16][257];

    const int tid  = threadIdx.x;
    const int lane = tid & 63;
    const int wv   = tid >> 6;
    const int m16  = lane & 15;
    const int quad = lane >> 4;
    const int rt   = blockIdx.x;
    const int row0 = rt * 16;

    floatx4 acc0 = {0.f,0.f,0.f,0.f}, acc1 = acc0, acc2 = acc0, acc3 = acc0;

    // A: slot (rt*20+s)*64 + lane ; B: slot (s*16 + wv*4+c)*64 + lane   (x8 bf16)
    const unsigned short* aptr = wsA + ((size_t)rt * 20 * 64 + lane) * 8;
    const unsigned short* bptr = wsB2 + ((size_t)(wv * 4) * 64 + lane) * 8;

    #pragma unroll
    for (int s = 0; s < NSTEP; ++s) {
        uint4 a  = *(const uint4*)(aptr + (size_t)s * 64 * 8);
        uint4 b0 = *(const uint4*)(bptr + ((size_t)s * 16 + 0) * 64 * 8);
        uint4 b1 = *(const uint4*)(bptr + ((size_t)s * 16 + 1) * 64 * 8);
        uint4 b2 = *(const uint4*)(bptr + ((size_t)s * 16 + 2) * 64 * 8);
        uint4 b3 = *(const uint4*)(bptr + ((size_t)s * 16 + 3) * 64 * 8);
        bf16x8 af = __builtin_bit_cast(bf16x8, a);
        acc0 = __builtin_amdgcn_mfma_f32_16x16x32_bf16(af, __builtin_bit_cast(bf16x8, b0), acc0, 0, 0, 0);
        acc1 = __builtin_amdgcn_mfma_f32_16x16x32_bf16(af, __builtin_bit_cast(bf16x8, b1), acc1, 0, 0, 0);
        acc2 = __builtin_amdgcn_mfma_f32_16x16x32_bf16(af, __builtin_bit_cast(bf16x8, b2), acc2, 0, 0, 0);
        acc3 = __builtin_amdgcn_mfma_f32_16x16x32_bf16(af, __builtin_bit_cast(bf16x8, b3), acc3, 0, 0, 0);
    }

    // C/D layout: col = lane&15, row = quad*4 + reg
    const float scale = 0.03952847075210474f;  // 1/sqrt(640)
    #pragma unroll
    for (int i = 0; i < 4; ++i) {
        int r = quad * 4 + i;
        phone[r][wv * 64 +  0 + m16] = acc0[i] * scale;
        phone[r][wv * 64 + 16 + m16] = acc1[i] * scale;
        phone[r][wv * 64 + 32 + m16] = acc2[i] * scale;
        phone[r][wv * 64 + 48 + m16] = acc3[i] * scale;
    }
    __syncthreads();

    // seg-max + log_softmax: 16 threads per row; thread handles m = l16 + 16j (j<6)
    const int r   = tid >> 4;
    const int l16 = tid & 15;
    float pmv[6];
    float mx = -INFINITY;
    #pragma unroll
    for (int j = 0; j < 6; ++j) {
        int m = l16 + j * 16;
        int c = cnt[m];
        const int* lst = csr + m * MAXL;
        float best = -INFINITY;
        for (int jj = 0; jj < c; ++jj) best = fmaxf(best, phone[r][lst[jj]]);
        pmv[j] = best;
        mx = fmaxf(mx, best);
    }
    #pragma unroll
    for (int d = 1; d < 16; d <<= 1) mx = fmaxf(mx, __shfl_xor(mx, d));
    float s = 0.f;
    #pragma unroll
    for (int j = 0; j < 6; ++j) s += __expf(pmv[j] - mx);
    #pragma unroll
    for (int d = 1; d < 16; d <<= 1) s += __shfl_xor(s, d);
    const float lse = mx + __logf(s);
    #pragma unroll
    for (int j = 0; j < 6; ++j)
        out[(size_t)(row0 + r) * NM + l16 + j * 16] = pmv[j] - lse;
}

extern "C" void kernel_launch(void* const* d_in, const int* in_sizes, int n_in,
                              void* d_out, int out_size, void* d_ws, size_t ws_size,
                              hipStream_t stream) {
    const float* enc     = (const float*)d_in[0];   // (8,1024,640) f32
    const float* f2p     = (const float*)d_in[1];   // (640,230) f32
    const float* mapping = (const float*)d_in[2];   // (96,230) f32
    float* out = (float*)d_out;                     // (8,1024,96) f32

    char* ws = (char*)d_ws;
    int* cnt = (int*)(ws + OFF_CNT);
    int* csr = (int*)(ws + OFF_CSR);
    unsigned short* wsB2 = (unsigned short*)(ws + OFF_B);
    unsigned short* wsA  = (unsigned short*)(ws + OFF_A);

    prep_kernel<<<2664, 256, 0, stream>>>(enc, f2p, mapping, cnt, csr, wsB2, wsA);
    fused_phonetics_kernel<<<NRT, 256, 0, stream>>>(wsA, wsB2, cnt, csr, out);
}